// Round 4
// baseline (824.657 us; speedup 1.0000x reference)
//
#include <hip/hip_runtime.h>

// EdgeSAGELayer: out = relu(concat(node_attr, scatter_mean(edge_attr*ew, tgt)) @ W.T + b) * nw
// N=100000, E=1250000, F=64, IN=128, OUT=128. f32 except edge_index (int32).
//
// R4: scatter-atomics (321us, atomic-RMW-bound: 560MB @ 1.74TB/s, VALU 11%)
// replaced by permutation-CSR build + gather. Atomics now only carry 4B index
// traffic; the 320MB edge_attr stream moves once, coalesced 256B/row.

#define EF 64
#define IN_CH 128
#define OUT_CH 128
#define K_TOT 192        // IN_CH + EF

// ---------------------------------------------------------------------------
// K1: degree histogram. deg[] pre-zeroed by memset.
// ---------------------------------------------------------------------------
__global__ __launch_bounds__(256) void degree_kernel(
    const int* __restrict__ tgt, int* __restrict__ deg, int E)
{
    const int e = blockIdx.x * blockDim.x + threadIdx.x;
    if (e < E) atomicAdd(&deg[tgt[e]], 1);
}

// ---------------------------------------------------------------------------
// K2: per-node contiguous range assignment via one global bump.
// base[n] = start slot; cursor[n] = running bump copy. No scan needed:
// gather only requires per-node contiguity, not any particular order.
// ---------------------------------------------------------------------------
__global__ __launch_bounds__(256) void assign_kernel(
    const int* __restrict__ deg, int* __restrict__ cursor0,
    int* __restrict__ base, int* __restrict__ cursor, int N)
{
    const int n = blockIdx.x * blockDim.x + threadIdx.x;
    if (n < N) {
        const int b = atomicAdd(cursor0, deg[n]);
        base[n] = b;
        cursor[n] = b;
    }
}

// ---------------------------------------------------------------------------
// K3: build permutation: slot -> edge id.
// ---------------------------------------------------------------------------
__global__ __launch_bounds__(256) void reorder_kernel(
    const int* __restrict__ tgt, int* __restrict__ cursor,
    int* __restrict__ perm, int E)
{
    const int e = blockIdx.x * blockDim.x + threadIdx.x;
    if (e < E) {
        const int pos = atomicAdd(&cursor[tgt[e]], 1);
        perm[pos] = e;
    }
}

// ---------------------------------------------------------------------------
// K4: gather-mean. One wave per node; lane i = feature i.
// Reads each edge_attr row once (256B coalesced, random position).
// Writes edge MEAN directly (division folded in here, GEMM reads it raw).
// ---------------------------------------------------------------------------
__global__ __launch_bounds__(256) void gather_mean_kernel(
    const float* __restrict__ edge_attr,   // [E, 64]
    const float* __restrict__ edge_weight, // [E]
    const int* __restrict__ perm,          // [E]
    const int* __restrict__ base,          // [N]
    const int* __restrict__ deg,           // [N]
    float* __restrict__ mean,              // [N, 64] output
    int N)
{
    const int n = (blockIdx.x * blockDim.x + threadIdx.x) >> 6;
    const int lane = threadIdx.x & 63;
    if (n >= N) return;

    const int s = base[n];
    const int d = deg[n];
    float acc = 0.0f;
    for (int i = 0; i < d; ++i) {
        const int e = perm[s + i];                          // wave-uniform broadcast
        acc += edge_attr[(size_t)e * EF + lane] * edge_weight[e];
    }
    mean[(size_t)n * EF + lane] = acc / (float)max(d, 1);
}

// ---------------------------------------------------------------------------
// K5: per-node GEMM + epilogue (unchanged structure from R3 except cnt
// division removed — mean[] arrives pre-divided).
//   h = [node_attr | mean]  (K=192); out = relu(h @ W.T + b) * node_weight
// Block = 256 threads, 64 nodes/block, thread = 4 nodes x 8 outs.
// W_lds chunk-permuted: pos(o) = (o>>3)*4 + (o&3) + ((o&4)?64:0) so compute
// ds_read_b128 spans 256B (2-way, free) instead of 32B stride (4-way).
// ---------------------------------------------------------------------------
#define NB 64
#define KT 64
#define HP 68

__device__ __forceinline__ int wpos(int o) {
    return ((o >> 3) << 2) + (o & 3) + ((o & 4) ? 64 : 0);
}

__global__ __launch_bounds__(256) void node_gemm_kernel(
    const float* __restrict__ node_attr,   // [N, 128]
    const float* __restrict__ mean,        // [N, 64] pre-divided
    const float* __restrict__ W,           // [128, 192]
    const float* __restrict__ b,           // [128]
    const float* __restrict__ node_weight, // [N]
    float* __restrict__ out,               // [N, 128]
    int N)
{
    __shared__ float W_lds[KT * OUT_CH];
    __shared__ float h_lds[KT * HP];

    const int tid   = threadIdx.x;
    const int node0 = blockIdx.x * NB;

    const int oc = tid & 15;
    const int o0 = oc * 8;
    const int n0 = (tid >> 4) * 4;

    const int s_node = tid >> 2;
    const int s_k0   = (tid & 3) * 16;
    const int w_o    = tid & 127;
    const int w_kh   = (tid >> 7) * 32;
    const int w_p    = wpos(w_o);

    float acc[4][8];
#pragma unroll
    for (int n = 0; n < 4; ++n)
#pragma unroll
        for (int j = 0; j < 8; ++j) acc[n][j] = 0.0f;

    const int gs_node = node0 + s_node;

    for (int kt = 0; kt < 3; ++kt) {
        const int k0 = kt * KT;
        __syncthreads();

        {
            const float* src = W + (size_t)w_o * K_TOT + k0 + w_kh;
#pragma unroll
            for (int i = 0; i < 32; i += 4) {
                const float4 wv = *reinterpret_cast<const float4*>(src + i);
                W_lds[(w_kh + i + 0) * OUT_CH + w_p] = wv.x;
                W_lds[(w_kh + i + 1) * OUT_CH + w_p] = wv.y;
                W_lds[(w_kh + i + 2) * OUT_CH + w_p] = wv.z;
                W_lds[(w_kh + i + 3) * OUT_CH + w_p] = wv.w;
            }
        }

        if (gs_node < N) {
            const float* src = (kt < 2)
                ? node_attr + (size_t)gs_node * IN_CH + k0 + s_k0
                : mean      + (size_t)gs_node * EF   + s_k0;
#pragma unroll
            for (int i = 0; i < 16; i += 4) {
                const float4 hv = *reinterpret_cast<const float4*>(src + i);
                h_lds[(s_k0 + i + 0) * HP + s_node] = hv.x;
                h_lds[(s_k0 + i + 1) * HP + s_node] = hv.y;
                h_lds[(s_k0 + i + 2) * HP + s_node] = hv.z;
                h_lds[(s_k0 + i + 3) * HP + s_node] = hv.w;
            }
        }
        __syncthreads();

#pragma unroll 4
        for (int k = 0; k < KT; ++k) {
            const float4 hv = *reinterpret_cast<const float4*>(&h_lds[k * HP + n0]);
            const float4 w0 = *reinterpret_cast<const float4*>(&W_lds[k * OUT_CH + oc * 4]);
            const float4 w1 = *reinterpret_cast<const float4*>(&W_lds[k * OUT_CH + 64 + oc * 4]);
            const float hh[4] = {hv.x, hv.y, hv.z, hv.w};
            const float ww[8] = {w0.x, w0.y, w0.z, w0.w, w1.x, w1.y, w1.z, w1.w};
#pragma unroll
            for (int n = 0; n < 4; ++n)
#pragma unroll
                for (int j = 0; j < 8; ++j)
                    acc[n][j] = fmaf(hh[n], ww[j], acc[n][j]);
        }
    }

    const float4 b0 = *reinterpret_cast<const float4*>(b + o0);
    const float4 b1 = *reinterpret_cast<const float4*>(b + o0 + 4);
    const float bb[8] = {b0.x, b0.y, b0.z, b0.w, b1.x, b1.y, b1.z, b1.w};

#pragma unroll
    for (int n = 0; n < 4; ++n) {
        const int gn = node0 + n0 + n;
        if (gn < N) {
            const float nw = node_weight[gn];
            float r[8];
#pragma unroll
            for (int j = 0; j < 8; ++j)
                r[j] = fmaxf(acc[n][j] + bb[j], 0.0f) * nw;
            float* dst = out + (size_t)gn * OUT_CH + o0;
            *reinterpret_cast<float4*>(dst)     = make_float4(r[0], r[1], r[2], r[3]);
            *reinterpret_cast<float4*>(dst + 4) = make_float4(r[4], r[5], r[6], r[7]);
        }
    }
}

// ---------------------------------------------------------------------------
extern "C" void kernel_launch(void* const* d_in, const int* in_sizes, int n_in,
                              void* d_out, int out_size, void* d_ws, size_t ws_size,
                              hipStream_t stream) {
    const int*   edge_index  = (const int*)d_in[0];   // [2, E], row 0 = targets
    const float* edge_attr   = (const float*)d_in[1]; // [E, 64]
    const float* node_attr   = (const float*)d_in[2]; // [N, 128]
    const float* edge_weight = (const float*)d_in[3]; // [E]
    const float* node_weight = (const float*)d_in[4]; // [N]
    const float* W           = (const float*)d_in[5]; // [128, 192]
    const float* b           = (const float*)d_in[6]; // [128]
    float* out = (float*)d_out;

    const int E = in_sizes[0] / 2;
    const int N = in_sizes[2] / IN_CH;

    // workspace layout (all fully written by kernels except deg/cursor0 -> memset)
    int*   deg     = (int*)d_ws;                 // [N]
    int*   cursor0 = deg + N;                    // [1]
    int*   base    = cursor0 + 1;                // [N]
    int*   cursor  = base + N;                   // [N]
    int*   perm    = cursor + N;                 // [E]
    float* mean    = (float*)(perm + E);         // [N, 64]
    // total: (3N+1+E)*4 + N*64*4 ~= 31.8 MB

    hipMemsetAsync(deg, 0, (size_t)(N + 1) * sizeof(int), stream);  // deg + cursor0

    const int eb = (E + 255) / 256;
    const int nb = (N + 255) / 256;

    degree_kernel <<<eb, 256, 0, stream>>>(edge_index, deg, E);
    assign_kernel <<<nb, 256, 0, stream>>>(deg, cursor0, base, cursor, N);
    reorder_kernel<<<eb, 256, 0, stream>>>(edge_index, cursor, perm, E);

    // gather: 4 waves/block, wave per node
    const int gb = (N + 3) / 4;
    gather_mean_kernel<<<gb, 256, 0, stream>>>(
        edge_attr, edge_weight, perm, base, deg, mean, N);

    const int gemm_blocks = (N + NB - 1) / NB;
    node_gemm_kernel<<<gemm_blocks, 256, 0, stream>>>(
        node_attr, mean, W, b, node_weight, out, N);
}

// Round 5
// 710.951 us; speedup vs baseline: 1.1599x; 1.1599x over previous
//
#include <hip/hip_runtime.h>

// EdgeSAGELayer: out = relu(concat(node_attr, scatter_mean(edge_attr*ew, tgt)) @ W.T + b) * nw
// N=100000, E=1250000, F=64, IN=128, OUT=128. f32 except edge_index (int32).
//
// R5: gather was latency-bound (237us, HBM 13.6%, VALU 8.9% -> MLP=1 serial
// chain). Fixes: (a) 8B {edge,weight} records so gather has one random
// stream; (b) 4-wide hand-unroll = 4 rows in flight; (c) assign_kernel's
// 100K single-address atomics -> block scan + 1 atomic/block.

#define EF 64
#define IN_CH 128
#define OUT_CH 128
#define K_TOT 192        // IN_CH + EF

// ---------------------------------------------------------------------------
// K1: degree histogram. deg[] pre-zeroed by memset.
// ---------------------------------------------------------------------------
__global__ __launch_bounds__(256) void degree_kernel(
    const int* __restrict__ tgt, int* __restrict__ deg, int E)
{
    const int e = blockIdx.x * blockDim.x + threadIdx.x;
    if (e < E) atomicAdd(&deg[tgt[e]], 1);
}

// ---------------------------------------------------------------------------
// K2: contiguous range assignment. Block-level scan: wave shfl_up scan,
// cross-wave combine in LDS, ONE global atomic per block (391 total).
// Order across blocks arbitrary (gather only needs per-node contiguity).
// ---------------------------------------------------------------------------
__global__ __launch_bounds__(256) void assign_kernel(
    const int* __restrict__ deg, int* __restrict__ cursor0,
    int* __restrict__ base, int* __restrict__ cursor, int N)
{
    const int tid  = threadIdx.x;
    const int n    = blockIdx.x * 256 + tid;
    const int lane = tid & 63;
    const int wv   = tid >> 6;

    const int d = (n < N) ? deg[n] : 0;

    // wave inclusive scan
    int x = d;
#pragma unroll
    for (int off = 1; off < 64; off <<= 1) {
        const int y = __shfl_up(x, off);
        if (lane >= off) x += y;
    }

    __shared__ int wsum[4];
    __shared__ int bbase;
    if (lane == 63) wsum[wv] = x;
    __syncthreads();

    if (tid == 0) {
        const int blockSum = wsum[0] + wsum[1] + wsum[2] + wsum[3];
        bbase = atomicAdd(cursor0, blockSum);
    }
    __syncthreads();

    int prev = 0;
    for (int w = 0; w < wv; ++w) prev += wsum[w];

    const int b = bbase + prev + (x - d);   // exclusive prefix
    if (n < N) { base[n] = b; cursor[n] = b; }
}

// ---------------------------------------------------------------------------
// K3: build 8B records {edge_id, edge_weight} at permuted slots.
// Reads tgt/edge_weight coalesced; scattered 8B writes into 10MB (L2-ok).
// ---------------------------------------------------------------------------
__global__ __launch_bounds__(256) void reorder_kernel(
    const int* __restrict__ tgt, const float* __restrict__ edge_weight,
    int* __restrict__ cursor, int2* __restrict__ rec, int E)
{
    const int e = blockIdx.x * blockDim.x + threadIdx.x;
    if (e < E) {
        const int pos = atomicAdd(&cursor[tgt[e]], 1);
        rec[pos] = make_int2(e, __float_as_int(edge_weight[e]));
    }
}

// ---------------------------------------------------------------------------
// K4: gather-mean. One wave per node; lane i = feature i.
// 4-wide unroll: 4 independent edge rows in flight (MLP=4).
// ---------------------------------------------------------------------------
__global__ __launch_bounds__(256) void gather_mean_kernel(
    const float* __restrict__ edge_attr,   // [E, 64]
    const int2* __restrict__ rec,          // [E] {e, ew}
    const int* __restrict__ base,          // [N]
    const int* __restrict__ deg,           // [N]
    float* __restrict__ mean,              // [N, 64] output
    int N)
{
    const int n = (blockIdx.x * blockDim.x + threadIdx.x) >> 6;
    const int lane = threadIdx.x & 63;
    if (n >= N) return;

    const int2* __restrict__ r = rec + base[n];
    const int d = deg[n];

    float a0 = 0.0f, a1 = 0.0f, a2 = 0.0f, a3 = 0.0f;
    int i = 0;
    for (; i + 4 <= d; i += 4) {
        const int2 r0 = r[i + 0];          // wave-uniform broadcasts
        const int2 r1 = r[i + 1];
        const int2 r2 = r[i + 2];
        const int2 r3 = r[i + 3];
        const float v0 = edge_attr[(size_t)r0.x * EF + lane];  // 4 rows in flight
        const float v1 = edge_attr[(size_t)r1.x * EF + lane];
        const float v2 = edge_attr[(size_t)r2.x * EF + lane];
        const float v3 = edge_attr[(size_t)r3.x * EF + lane];
        a0 = fmaf(v0, __int_as_float(r0.y), a0);
        a1 = fmaf(v1, __int_as_float(r1.y), a1);
        a2 = fmaf(v2, __int_as_float(r2.y), a2);
        a3 = fmaf(v3, __int_as_float(r3.y), a3);
    }
    for (; i < d; ++i) {
        const int2 ri = r[i];
        a0 = fmaf(edge_attr[(size_t)ri.x * EF + lane], __int_as_float(ri.y), a0);
    }

    const float s = (a0 + a1) + (a2 + a3);
    mean[(size_t)n * EF + lane] = s / (float)max(d, 1);
}

// ---------------------------------------------------------------------------
// K5: per-node GEMM + epilogue (unchanged from R4).
//   h = [node_attr | mean]  (K=192); out = relu(h @ W.T + b) * node_weight
// W_lds chunk-permuted: pos(o) = (o>>3)*4 + (o&3) + ((o&4)?64:0).
// ---------------------------------------------------------------------------
#define NB 64
#define KT 64
#define HP 68

__device__ __forceinline__ int wpos(int o) {
    return ((o >> 3) << 2) + (o & 3) + ((o & 4) ? 64 : 0);
}

__global__ __launch_bounds__(256) void node_gemm_kernel(
    const float* __restrict__ node_attr,   // [N, 128]
    const float* __restrict__ mean,        // [N, 64] pre-divided
    const float* __restrict__ W,           // [128, 192]
    const float* __restrict__ b,           // [128]
    const float* __restrict__ node_weight, // [N]
    float* __restrict__ out,               // [N, 128]
    int N)
{
    __shared__ float W_lds[KT * OUT_CH];
    __shared__ float h_lds[KT * HP];

    const int tid   = threadIdx.x;
    const int node0 = blockIdx.x * NB;

    const int oc = tid & 15;
    const int o0 = oc * 8;
    const int n0 = (tid >> 4) * 4;

    const int s_node = tid >> 2;
    const int s_k0   = (tid & 3) * 16;
    const int w_o    = tid & 127;
    const int w_kh   = (tid >> 7) * 32;
    const int w_p    = wpos(w_o);

    float acc[4][8];
#pragma unroll
    for (int n = 0; n < 4; ++n)
#pragma unroll
        for (int j = 0; j < 8; ++j) acc[n][j] = 0.0f;

    const int gs_node = node0 + s_node;

    for (int kt = 0; kt < 3; ++kt) {
        const int k0 = kt * KT;
        __syncthreads();

        {
            const float* src = W + (size_t)w_o * K_TOT + k0 + w_kh;
#pragma unroll
            for (int i = 0; i < 32; i += 4) {
                const float4 wv = *reinterpret_cast<const float4*>(src + i);
                W_lds[(w_kh + i + 0) * OUT_CH + w_p] = wv.x;
                W_lds[(w_kh + i + 1) * OUT_CH + w_p] = wv.y;
                W_lds[(w_kh + i + 2) * OUT_CH + w_p] = wv.z;
                W_lds[(w_kh + i + 3) * OUT_CH + w_p] = wv.w;
            }
        }

        if (gs_node < N) {
            const float* src = (kt < 2)
                ? node_attr + (size_t)gs_node * IN_CH + k0 + s_k0
                : mean      + (size_t)gs_node * EF   + s_k0;
#pragma unroll
            for (int i = 0; i < 16; i += 4) {
                const float4 hv = *reinterpret_cast<const float4*>(src + i);
                h_lds[(s_k0 + i + 0) * HP + s_node] = hv.x;
                h_lds[(s_k0 + i + 1) * HP + s_node] = hv.y;
                h_lds[(s_k0 + i + 2) * HP + s_node] = hv.z;
                h_lds[(s_k0 + i + 3) * HP + s_node] = hv.w;
            }
        }
        __syncthreads();

#pragma unroll 4
        for (int k = 0; k < KT; ++k) {
            const float4 hv = *reinterpret_cast<const float4*>(&h_lds[k * HP + n0]);
            const float4 w0 = *reinterpret_cast<const float4*>(&W_lds[k * OUT_CH + oc * 4]);
            const float4 w1 = *reinterpret_cast<const float4*>(&W_lds[k * OUT_CH + 64 + oc * 4]);
            const float hh[4] = {hv.x, hv.y, hv.z, hv.w};
            const float ww[8] = {w0.x, w0.y, w0.z, w0.w, w1.x, w1.y, w1.z, w1.w};
#pragma unroll
            for (int n = 0; n < 4; ++n)
#pragma unroll
                for (int j = 0; j < 8; ++j)
                    acc[n][j] = fmaf(hh[n], ww[j], acc[n][j]);
        }
    }

    const float4 b0 = *reinterpret_cast<const float4*>(b + o0);
    const float4 b1 = *reinterpret_cast<const float4*>(b + o0 + 4);
    const float bb[8] = {b0.x, b0.y, b0.z, b0.w, b1.x, b1.y, b1.z, b1.w};

#pragma unroll
    for (int n = 0; n < 4; ++n) {
        const int gn = node0 + n0 + n;
        if (gn < N) {
            const float nw = node_weight[gn];
            float r[8];
#pragma unroll
            for (int j = 0; j < 8; ++j)
                r[j] = fmaxf(acc[n][j] + bb[j], 0.0f) * nw;
            float* dst = out + (size_t)gn * OUT_CH + o0;
            *reinterpret_cast<float4*>(dst)     = make_float4(r[0], r[1], r[2], r[3]);
            *reinterpret_cast<float4*>(dst + 4) = make_float4(r[4], r[5], r[6], r[7]);
        }
    }
}

// ---------------------------------------------------------------------------
extern "C" void kernel_launch(void* const* d_in, const int* in_sizes, int n_in,
                              void* d_out, int out_size, void* d_ws, size_t ws_size,
                              hipStream_t stream) {
    const int*   edge_index  = (const int*)d_in[0];   // [2, E], row 0 = targets
    const float* edge_attr   = (const float*)d_in[1]; // [E, 64]
    const float* node_attr   = (const float*)d_in[2]; // [N, 128]
    const float* edge_weight = (const float*)d_in[3]; // [E]
    const float* node_weight = (const float*)d_in[4]; // [N]
    const float* W           = (const float*)d_in[5]; // [128, 192]
    const float* b           = (const float*)d_in[6]; // [128]
    float* out = (float*)d_out;

    const int E = in_sizes[0] / 2;
    const int N = in_sizes[2] / IN_CH;

    // workspace layout (~36.8 MB)
    int*   deg     = (int*)d_ws;                 // [N]
    int*   cursor0 = deg + N;                    // [1]
    int*   base    = cursor0 + 1;                // [N]
    int*   cursor  = base + N;                   // [N]
    int2*  rec     = (int2*)(cursor + N);        // [E] {e, ew}
    float* mean    = (float*)(rec + E);          // [N, 64]

    hipMemsetAsync(deg, 0, (size_t)(N + 1) * sizeof(int), stream);  // deg + cursor0

    const int eb = (E + 255) / 256;
    const int nb = (N + 255) / 256;

    degree_kernel <<<eb, 256, 0, stream>>>(edge_index, deg, E);
    assign_kernel <<<nb, 256, 0, stream>>>(deg, cursor0, base, cursor, N);
    reorder_kernel<<<eb, 256, 0, stream>>>(edge_index, edge_weight, cursor, rec, E);

    // gather: 4 waves/block, wave per node
    const int gb = (N + 3) / 4;
    gather_mean_kernel<<<gb, 256, 0, stream>>>(
        edge_attr, rec, base, deg, mean, N);

    const int gemm_blocks = (N + NB - 1) / NB;
    node_gemm_kernel<<<gemm_blocks, 256, 0, stream>>>(
        node_attr, mean, W, b, node_weight, out, N);
}